// Round 10
// baseline (5228.743 us; speedup 1.0000x reference)
//
#include <hip/hip_runtime.h>
#include <hip/hip_bf16.h>
#include <stdint.h>

#define B_  256
#define T_  512
#define H_  1024
#define BH  (B_ * H_)

typedef float  f32x4  __attribute__((ext_vector_type(4)));
typedef float  f32x16 __attribute__((ext_vector_type(16)));
typedef __bf16 bf16x8 __attribute__((ext_vector_type(8)));

__device__ inline ushort f2bf(float f) {
  union { float f; uint32_t u; } v; v.f = f;
  uint32_t u = v.u;
  return (ushort)((u + 0x7fffu + ((u >> 16) & 1u)) >> 16);   // RNE
}
__device__ inline float bf2f(ushort h) {
  union { uint32_t u; float f; } v; v.u = ((uint32_t)h) << 16;
  return v.f;
}
// packed f32x2 -> bf16x2 (low = a, high = b), RNE in HW
__device__ inline uint32_t cvtpk(float a, float b) {
  uint32_t r;
  asm("v_cvt_pk_bf16_f32 %0, %1, %2" : "=v"(r) : "v"(a), "v"(b));
  return r;
}
__device__ inline bf16x8 ld_bf8(const ushort* p) {
  union { uint4 u; bf16x8 b; } v;
  v.u = *(const uint4*)p;
  return v.b;
}
__device__ inline bf16x8 as_bf8(uint4 u) {
  union { uint4 a; bf16x8 b; } v; v.a = u; return v.b;
}
// coherent (device-scope, L2-bypass) 16B load, UNTRACKED: caller waits vmcnt.
__device__ inline uint4 ld16_sc1(const ushort* p) {
  uint4 r;
  asm volatile("global_load_dwordx4 %0, %1, off sc1" : "=&v"(r) : "v"(p));
  return r;
}
// plain cached 2B load, untracked (xp prefetch)
__device__ inline uint32_t ld2_pf(const ushort* p) {
  uint32_t r;
  asm volatile("global_load_ushort %0, %1, off" : "=&v"(r) : "v"(p));
  return r;
}
// device-scope 2B store (to coherence point; visible to all XCDs)
__device__ inline void st_bf_coh(ushort* p, ushort v) {
  asm volatile("global_store_short %0, %1, off sc1" :: "v"(p), "v"((uint32_t)v) : "memory");
}
__device__ inline float tanh_fast(float x) {
  float xc = fminf(fmaxf(x, -15.f), 15.f);
  float e  = __expf(2.f * xc);
  return (e - 1.f) * __builtin_amdgcn_rcpf(e + 1.f);
}

// ------------------------------------------------- x_proj = xs @ Wx^T + bias
// (r8 version — passed). Output bf16 in (T, B, H) layout.
__global__ __launch_bounds__(256) void xproj_gemm(const float* __restrict__ xs,
                                                  const float* __restrict__ W,
                                                  const float* __restrict__ bias,
                                                  ushort* __restrict__ xp) {
  __shared__ ushort As[128 * 32];
  __shared__ ushort Bs[128 * 32];
  const int bid = blockIdx.x;
  const int mt = bid >> 3, nt = bid & 7;
  const int tid = threadIdx.x;
  const int lane = tid & 63, wid = tid >> 6;
  const int wr = wid >> 1, wc = wid & 1;
  const int lr = lane & 15, lq = lane >> 4;

  const int srow = tid >> 1, scol = (tid & 1) * 16;
  const float* ag = xs + (size_t)(mt * 128 + srow) * 1024 + scol;
  const float* bg = W  + (size_t)(nt * 128 + srow) * 2048 + scol;
  ushort* as = As + srow * 32 + scol;
  ushort* bs = Bs + srow * 32 + scol;

  f32x4 acc[4][4];
#pragma unroll
  for (int m = 0; m < 4; ++m)
#pragma unroll
    for (int n = 0; n < 4; ++n) acc[m][n] = (f32x4){0.f, 0.f, 0.f, 0.f};

  for (int kc = 0; kc < 32; ++kc) {
    float4 a0 = *(const float4*)(ag + kc * 32);
    float4 a1 = *(const float4*)(ag + kc * 32 + 4);
    float4 a2 = *(const float4*)(ag + kc * 32 + 8);
    float4 a3 = *(const float4*)(ag + kc * 32 + 12);
    float4 b0 = *(const float4*)(bg + kc * 32);
    float4 b1 = *(const float4*)(bg + kc * 32 + 4);
    float4 b2 = *(const float4*)(bg + kc * 32 + 8);
    float4 b3 = *(const float4*)(bg + kc * 32 + 12);
    __syncthreads();
    {
      uint4 w0, w1;
      w0.x = cvtpk(a0.x, a0.y); w0.y = cvtpk(a0.z, a0.w);
      w0.z = cvtpk(a1.x, a1.y); w0.w = cvtpk(a1.z, a1.w);
      w1.x = cvtpk(a2.x, a2.y); w1.y = cvtpk(a2.z, a2.w);
      w1.z = cvtpk(a3.x, a3.y); w1.w = cvtpk(a3.z, a3.w);
      *(uint4*)as       = w0;
      *(uint4*)(as + 8) = w1;
      w0.x = cvtpk(b0.x, b0.y); w0.y = cvtpk(b0.z, b0.w);
      w0.z = cvtpk(b1.x, b1.y); w0.w = cvtpk(b1.z, b1.w);
      w1.x = cvtpk(b2.x, b2.y); w1.y = cvtpk(b2.z, b2.w);
      w1.z = cvtpk(b3.x, b3.y); w1.w = cvtpk(b3.z, b3.w);
      *(uint4*)bs       = w0;
      *(uint4*)(bs + 8) = w1;
    }
    __syncthreads();
    bf16x8 af[4], bfv[4];
#pragma unroll
    for (int m = 0; m < 4; ++m)
      af[m] = ld_bf8(As + (wr * 64 + m * 16 + lr) * 32 + lq * 8);
#pragma unroll
    for (int n = 0; n < 4; ++n)
      bfv[n] = ld_bf8(Bs + (wc * 64 + n * 16 + lr) * 32 + lq * 8);
#pragma unroll
    for (int m = 0; m < 4; ++m)
#pragma unroll
      for (int n = 0; n < 4; ++n)
        acc[m][n] = __builtin_amdgcn_mfma_f32_16x16x32_bf16(af[m], bfv[n], acc[m][n], 0, 0, 0);
  }

#pragma unroll
  for (int n = 0; n < 4; ++n) {
    int gn = nt * 128 + wc * 64 + n * 16 + lr;
    float bv = bias[gn];
#pragma unroll
    for (int m = 0; m < 4; ++m) {
      int gmb = mt * 128 + wr * 64 + m * 16 + lq * 4;
#pragma unroll
      for (int r = 0; r < 4; ++r) {
        int gm = gmb + r;
        int bi = gm >> 9, ti = gm & 511;     // m = b*512 + t
        xp[((size_t)ti * B_ + bi) * H_ + gn] = f2bf(acc[m][n][r] + bv);
      }
    }
  }
}

// ----------------------------------------------------------- persistent scan
// MODE 0: r8 EXACT (output path). MODE 1: ablation, poll elided (no inter-wg
// waiting; posts kept; scratch buffers; 128 steps). MODE 2: MODE1 + A-load
// waitcnts elided (loads issue, MFMA reads stale regs — garbage data, scratch
// only) -> compute + store-drain floor. real-V1 = coupling cost; V1-V2 =
// exposed A-load latency.
template <int MODE>
__global__ __launch_bounds__(128) void rnn_scan(const float* __restrict__ W,
                                                const ushort* __restrict__ xp,
                                                ushort* __restrict__ hb,
                                                float* __restrict__ out,
                                                int* __restrict__ flags) {
  constexpr int TS = (MODE == 0) ? T_ : 128;
  __shared__ ushort Bsm[64 * 1024];          // 128 KB: Wh cols [ct*64, +64)
  __shared__ float  Psm[32][68];             // 8.7 KB K-half partials (pad 68)
  const int bid = blockIdx.x, tid = threadIdx.x;
  const int rt = bid & 7, ct = bid >> 3;     // 8 row-tiles x 16 col-tiles
  const int lane = tid & 63;
  const int kh = tid >> 6;                   // wave: K-half [kh*512, +512)
  const int l31 = lane & 31, l5 = lane >> 5;
  const int rbase = rt * 32;

  // ---- one-time stage: Wh (fp32, W[:,1024:]) -> bf16 LDS, 16B-granule swizzle
  {
    const int c    = tid >> 1;               // 0..63  (local col)
    const int half = tid & 1;                // k-half (512 floats)
    const float* src = W + (size_t)(ct * 64 + c) * 2048 + 1024 + half * 512;
    char* dst = (char*)Bsm + c * 2048;
    const int sw = (c & 7) << 4;
#pragma unroll
    for (int q = 0; q < 64; ++q) {
      float4 f0 = *(const float4*)(src + q * 8);
      float4 f1 = *(const float4*)(src + q * 8 + 4);
      uint4 w;
      w.x = cvtpk(f0.x, f0.y); w.y = cvtpk(f0.z, f0.w);
      w.z = cvtpk(f1.x, f1.y); w.w = cvtpk(f1.z, f1.w);
      *(uint4*)(dst + ((half * 1024 + q * 16) ^ sw)) = w;
    }
  }
  __syncthreads();

  // B frag: col = f*32 + l31, k = kh*512 + c*16 + l5*8  (r1-verified layout)
  const int swz = (l31 & 7) << 4;
  const char* bp0 = (char*)Bsm + l31 * 2048 + kh * 1024;        // frag 0
  const char* bp1 = (char*)Bsm + (32 + l31) * 2048 + kh * 1024; // frag 1
  // C/D rows (m74/m101): row = (r&3) + 8*(r>>2) + 4*l5, col = l31
  int crow[16];
#pragma unroll
  for (int r = 0; r < 16; ++r) crow[r] = (r & 3) + 8 * (r >> 2) + 4 * l5;

  uint32_t xv[32];                           // k1 wave: next step's xp slice

  // ---- step 0: h1 = tanh(xp[0])  (h0 == 0); k1 wave stores + prefetches
  if (kh) {
#pragma unroll
    for (int f = 0; f < 2; ++f)
#pragma unroll
      for (int r = 0; r < 16; ++r) {
        int gr = rbase + crow[r], gc = ct * 64 + f * 32 + l31;
        float v = tanh_fast(bf2f(xp[(size_t)gr * H_ + gc]));
        st_bf_coh(hb + (size_t)gr * H_ + gc, f2bf(v));
      }
#pragma unroll
    for (int f = 0; f < 2; ++f)
#pragma unroll
      for (int r = 0; r < 16; ++r) {
        int gr = rbase + crow[r], gc = ct * 64 + f * 32 + l31;
        xv[f * 16 + r] = ld2_pf(xp + (size_t)BH + (size_t)gr * H_ + gc);
      }
    asm volatile("s_waitcnt vmcnt(32)" ::: "memory");  // 32 stores drained
  }
  __syncthreads();
  if (tid == 0)
    __hip_atomic_store(flags + bid * 16, 1, __ATOMIC_RELAXED, __HIP_MEMORY_SCOPE_AGENT);
  if constexpr (MODE == 0) {
    if (tid < 16) {
      while (__hip_atomic_load(flags + (tid * 8 + rt) * 16, __ATOMIC_RELAXED,
                               __HIP_MEMORY_SCOPE_AGENT) < 1) {}
    }
  }
  __syncthreads();

  for (int s = 1; s < TS; ++s) {
    const ushort* hprev = hb + ((s + 1) & 1) * BH;
    ushort*       hnext = hb + (s & 1) * BH;
    // A frag: row = rbase + l31, k = kh*512 + c*16 + l5*8  (r1-verified)
    const ushort* arow = hprev + (size_t)(rbase + l31) * H_ + kh * 512 + l5 * 8;

    // issue ALL 32 disjoint A-chunk loads (this wave's K-half)
    uint4 A[32];
#pragma unroll
    for (int c = 0; c < 32; ++c) A[c] = ld16_sc1(arow + c * 16);

    if constexpr (MODE < 2) {
      asm volatile("s_waitcnt vmcnt(16)" ::: "memory");  // chunks 0..15 ready
      __builtin_amdgcn_sched_barrier(0);
    }

    f32x16 acc0, acc1;
#pragma unroll
    for (int i = 0; i < 16; ++i) { acc0[i] = 0.f; acc1[i] = 0.f; }

#pragma unroll
    for (int c = 0; c < 16; ++c) {
      bf16x8 av = as_bf8(A[c]);
      const int off = ((c * 32) | (l5 * 16)) ^ swz;
      acc0 = __builtin_amdgcn_mfma_f32_32x32x16_bf16(av, *(const bf16x8*)(bp0 + off), acc0, 0, 0, 0);
      acc1 = __builtin_amdgcn_mfma_f32_32x32x16_bf16(av, *(const bf16x8*)(bp1 + off), acc1, 0, 0, 0);
    }
    if constexpr (MODE < 2) {
      asm volatile("s_waitcnt vmcnt(0)" ::: "memory");
      __builtin_amdgcn_sched_barrier(0);
    }
#pragma unroll
    for (int c = 16; c < 32; ++c) {
      bf16x8 av = as_bf8(A[c]);
      const int off = ((c * 32) | (l5 * 16)) ^ swz;
      acc0 = __builtin_amdgcn_mfma_f32_32x32x16_bf16(av, *(const bf16x8*)(bp0 + off), acc0, 0, 0, 0);
      acc1 = __builtin_amdgcn_mfma_f32_32x32x16_bf16(av, *(const bf16x8*)(bp1 + off), acc1, 0, 0, 0);
    }

    // K-half handoff: k0 writes partials, k1 combines
    if (!kh) {
#pragma unroll
      for (int r = 0; r < 16; ++r) {
        Psm[crow[r]][l31]      = acc0[r];
        Psm[crow[r]][32 + l31] = acc1[r];
      }
    }
    __syncthreads();

    if (s < T_ - 1) {
      if (kh) {
#pragma unroll
        for (int r = 0; r < 16; ++r) {
          int gr = rbase + crow[r];
          float v0 = tanh_fast(acc0[r] + Psm[crow[r]][l31]      + bf2f((ushort)xv[r]));
          float v1 = tanh_fast(acc1[r] + Psm[crow[r]][32 + l31] + bf2f((ushort)xv[16 + r]));
          st_bf_coh(hnext + (size_t)gr * H_ + ct * 64 + l31,      f2bf(v0));
          st_bf_coh(hnext + (size_t)gr * H_ + ct * 64 + 32 + l31, f2bf(v1));
        }
        // prefetch next step's xp slice (flies during barrier)
        const ushort* xnext = xp + (size_t)(s + 1) * BH;
#pragma unroll
        for (int f = 0; f < 2; ++f)
#pragma unroll
          for (int r = 0; r < 16; ++r) {
            int gr = rbase + crow[r], gc = ct * 64 + f * 32 + l31;
            xv[f * 16 + r] = ld2_pf(xnext + (size_t)gr * H_ + gc);
          }
        asm volatile("s_waitcnt vmcnt(32)" ::: "memory");  // 32 stores retired
      }
      __syncthreads();
      if (tid == 0)
        __hip_atomic_store(flags + bid * 16, s + 1, __ATOMIC_RELAXED, __HIP_MEMORY_SCOPE_AGENT);
      if constexpr (MODE == 0) {
        if (tid < 16) {
          while (__hip_atomic_load(flags + (tid * 8 + rt) * 16, __ATOMIC_RELAXED,
                                   __HIP_MEMORY_SCOPE_AGENT) < s + 1) {}
        }
      }
      __syncthreads();
    } else {
      if (kh) {
#pragma unroll
        for (int r = 0; r < 16; ++r) {
          int gr = rbase + crow[r];
          float v0 = tanh_fast(acc0[r] + Psm[crow[r]][l31]      + bf2f((ushort)xv[r]));
          float v1 = tanh_fast(acc1[r] + Psm[crow[r]][32 + l31] + bf2f((ushort)xv[16 + r]));
          out[(size_t)gr * H_ + ct * 64 + l31]                   = v0;
          out[(size_t)gr * H_ + ct * 64 + 32 + l31]              = v1;
          out[(size_t)BH + (size_t)gr * H_ + ct * 64 + l31]      = v0;
          out[(size_t)BH + (size_t)gr * H_ + ct * 64 + 32 + l31] = v1;
        }
      }
    }
  }
}

// ---------------------------------------------------------------------- host
extern "C" void kernel_launch(void* const* d_in, const int* in_sizes, int n_in,
                              void* d_out, int out_size, void* d_ws, size_t ws_size,
                              hipStream_t stream) {
  const float* xs   = (const float*)d_in[0];
  const float* W    = (const float*)d_in[1];
  const float* bias = (const float*)d_in[2];
  float* out = (float*)d_out;
  char*  ws  = (char*)d_ws;

  const size_t XP_OFF  = 0;                      // bf16 x_proj (T,B,H): 256 MiB
  const size_t HB_OFF  = 268435456;              // bf16 h double-buffer: 1 MiB
  const size_t BR_OFF  = HB_OFF + 1048576;       // flags: 8 KiB (host memset)
  const size_t HB2_OFF = BR_OFF + 8192;          // ablation h scratch: 1 MiB
  const size_t BR2_OFF = HB2_OFF + 1048576;      // ablation flags: 8 KiB
  const size_t NEED    = BR2_OFF + 8192;
  if (ws_size < NEED) {
    hipMemsetAsync(d_out, 0, (size_t)out_size * 4, stream);
    return;
  }

  ushort* xp     = (ushort*)(ws + XP_OFF);
  ushort* hb     = (ushort*)(ws + HB_OFF);
  int*    flags  = (int*)(ws + BR_OFF);
  ushort* hb2    = (ushort*)(ws + HB2_OFF);
  int*    flags2 = (int*)(ws + BR2_OFF);

  // flags must be fresh every call (ws not re-poisoned between replays)
  hipMemsetAsync(flags,  0, 128 * 16 * sizeof(int), stream);
  hipMemsetAsync(flags2, 0, 128 * 16 * sizeof(int), stream);

  xproj_gemm<<<8192, 256, 0, stream>>>(xs, W, bias, xp);
  // real (output) dispatch — r8-exact protocol
  rnn_scan<0><<<128, 128, 0, stream>>>(W, xp, hb, out, flags);
  // ablation dispatches (scratch only, 128 steps each):
  // V1 = no poll (coupling removed); V2 = V1 + no A-load waits (latency removed)
  rnn_scan<1><<<128, 128, 0, stream>>>(W, xp, hb2, (float*)hb2, flags2);
  rnn_scan<2><<<128, 128, 0, stream>>>(W, xp, hb2, (float*)hb2, flags2);
}

// Round 11
// 2944.448 us; speedup vs baseline: 1.7758x; 1.7758x over previous
//
#include <hip/hip_runtime.h>
#include <hip/hip_bf16.h>
#include <stdint.h>

#define B_  256
#define T_  512
#define H_  1024
#define BH  (B_ * H_)

typedef float  f32x4  __attribute__((ext_vector_type(4)));
typedef float  f32x16 __attribute__((ext_vector_type(16)));
typedef __bf16 bf16x8 __attribute__((ext_vector_type(8)));

__device__ inline ushort f2bf(float f) {
  union { float f; uint32_t u; } v; v.f = f;
  uint32_t u = v.u;
  return (ushort)((u + 0x7fffu + ((u >> 16) & 1u)) >> 16);   // RNE
}
__device__ inline float bf2f(ushort h) {
  union { uint32_t u; float f; } v; v.u = ((uint32_t)h) << 16;
  return v.f;
}
// packed f32x2 -> bf16x2 (low = a, high = b), RNE in HW
__device__ inline uint32_t cvtpk(float a, float b) {
  uint32_t r;
  asm("v_cvt_pk_bf16_f32 %0, %1, %2" : "=v"(r) : "v"(a), "v"(b));
  return r;
}
__device__ inline bf16x8 ld_bf8(const ushort* p) {
  union { uint4 u; bf16x8 b; } v;
  v.u = *(const uint4*)p;
  return v.b;
}
__device__ inline bf16x8 as_bf8(uint4 u) {
  union { uint4 a; bf16x8 b; } v; v.a = u; return v.b;
}
// coherent (device-scope, L2-bypass) 16B load, UNTRACKED: caller waits vmcnt.
__device__ inline uint4 ld16_sc1(const ushort* p) {
  uint4 r;
  asm volatile("global_load_dwordx4 %0, %1, off sc1" : "=&v"(r) : "v"(p));
  return r;
}
// plain cached 8B load, untracked (xp prefetch)
__device__ inline uint2 ld8_pf(const ushort* p) {
  uint2 r;
  asm volatile("global_load_dwordx2 %0, %1, off" : "=&v"(r) : "v"(p));
  return r;
}
// device-scope 8B store (to coherence point; visible to all XCDs)
__device__ inline void st8_coh(ushort* p, uint2 v) {
  asm volatile("global_store_dwordx2 %0, %1, off sc1" :: "v"(p), "v"(v) : "memory");
}
__device__ inline float tanh_fast(float x) {
  float xc = fminf(fmaxf(x, -15.f), 15.f);
  float e  = __expf(2.f * xc);
  return (e - 1.f) * __builtin_amdgcn_rcpf(e + 1.f);
}

// ------------------------------------------------- x_proj = xs @ Wx^T + bias
// (r8 version — passed). Output bf16 in (T, B, H) layout.
__global__ __launch_bounds__(256) void xproj_gemm(const float* __restrict__ xs,
                                                  const float* __restrict__ W,
                                                  const float* __restrict__ bias,
                                                  ushort* __restrict__ xp) {
  __shared__ ushort As[128 * 32];
  __shared__ ushort Bs[128 * 32];
  const int bid = blockIdx.x;
  const int mt = bid >> 3, nt = bid & 7;
  const int tid = threadIdx.x;
  const int lane = tid & 63, wid = tid >> 6;
  const int wr = wid >> 1, wc = wid & 1;
  const int lr = lane & 15, lq = lane >> 4;

  const int srow = tid >> 1, scol = (tid & 1) * 16;
  const float* ag = xs + (size_t)(mt * 128 + srow) * 1024 + scol;
  const float* bg = W  + (size_t)(nt * 128 + srow) * 2048 + scol;
  ushort* as = As + srow * 32 + scol;
  ushort* bs = Bs + srow * 32 + scol;

  f32x4 acc[4][4];
#pragma unroll
  for (int m = 0; m < 4; ++m)
#pragma unroll
    for (int n = 0; n < 4; ++n) acc[m][n] = (f32x4){0.f, 0.f, 0.f, 0.f};

  for (int kc = 0; kc < 32; ++kc) {
    float4 a0 = *(const float4*)(ag + kc * 32);
    float4 a1 = *(const float4*)(ag + kc * 32 + 4);
    float4 a2 = *(const float4*)(ag + kc * 32 + 8);
    float4 a3 = *(const float4*)(ag + kc * 32 + 12);
    float4 b0 = *(const float4*)(bg + kc * 32);
    float4 b1 = *(const float4*)(bg + kc * 32 + 4);
    float4 b2 = *(const float4*)(bg + kc * 32 + 8);
    float4 b3 = *(const float4*)(bg + kc * 32 + 12);
    __syncthreads();
    {
      uint4 w0, w1;
      w0.x = cvtpk(a0.x, a0.y); w0.y = cvtpk(a0.z, a0.w);
      w0.z = cvtpk(a1.x, a1.y); w0.w = cvtpk(a1.z, a1.w);
      w1.x = cvtpk(a2.x, a2.y); w1.y = cvtpk(a2.z, a2.w);
      w1.z = cvtpk(a3.x, a3.y); w1.w = cvtpk(a3.z, a3.w);
      *(uint4*)as       = w0;
      *(uint4*)(as + 8) = w1;
      w0.x = cvtpk(b0.x, b0.y); w0.y = cvtpk(b0.z, b0.w);
      w0.z = cvtpk(b1.x, b1.y); w0.w = cvtpk(b1.z, b1.w);
      w1.x = cvtpk(b2.x, b2.y); w1.y = cvtpk(b2.z, b2.w);
      w1.z = cvtpk(b3.x, b3.y); w1.w = cvtpk(b3.z, b3.w);
      *(uint4*)bs       = w0;
      *(uint4*)(bs + 8) = w1;
    }
    __syncthreads();
    bf16x8 af[4], bfv[4];
#pragma unroll
    for (int m = 0; m < 4; ++m)
      af[m] = ld_bf8(As + (wr * 64 + m * 16 + lr) * 32 + lq * 8);
#pragma unroll
    for (int n = 0; n < 4; ++n)
      bfv[n] = ld_bf8(Bs + (wc * 64 + n * 16 + lr) * 32 + lq * 8);
#pragma unroll
    for (int m = 0; m < 4; ++m)
#pragma unroll
      for (int n = 0; n < 4; ++n)
        acc[m][n] = __builtin_amdgcn_mfma_f32_16x16x32_bf16(af[m], bfv[n], acc[m][n], 0, 0, 0);
  }

#pragma unroll
  for (int n = 0; n < 4; ++n) {
    int gn = nt * 128 + wc * 64 + n * 16 + lr;
    float bv = bias[gn];
#pragma unroll
    for (int m = 0; m < 4; ++m) {
      int gmb = mt * 128 + wr * 64 + m * 16 + lq * 4;
#pragma unroll
      for (int r = 0; r < 4; ++r) {
        int gm = gmb + r;
        int bi = gm >> 9, ti = gm & 511;     // m = b*512 + t
        xp[((size_t)ti * B_ + bi) * H_ + gn] = f2bf(acc[m][n][r] + bv);
      }
    }
  }
}

// ----------------------------------------------------------- persistent scan
// 256 wgs (8 rt x 32 ct) x 256 thr. wg = 32 rows x 32 cols; wave = K-quarter
// (256 k) of the whole tile via 32x32x16 MFMA (r8-proven layouts). A-loads:
// 16 dwordx4 sc1 per wave, disjoint. Partials through Psm[4] (deterministic).
// Epilogue repacked across ALL 256 threads: (row, 4 cols)/thread -> ONE sc1
// dwordx2 h-store + ONE dwordx2 xp prefetch. Flag protocol r5-proven.
__global__ __launch_bounds__(256) void rnn_scan(const float* __restrict__ W,
                                                const ushort* __restrict__ xp,
                                                ushort* __restrict__ hb,
                                                float* __restrict__ out,
                                                int* __restrict__ flags) {
  __shared__ ushort Bsm[32 * 1024];          // 64 KB: Wh cols [ct*32, +32)
  __shared__ float  Psm[4][32][68];          // 34 KB K-quarter partials
  const int bid = blockIdx.x, tid = threadIdx.x;
  const int rt = bid >> 5, ct = bid & 31;    // 8 row-tiles x 32 col-tiles
  const int lane = tid & 63;
  const int kq = tid >> 6;                   // wave: K-quarter [kq*256, +256)
  const int l31 = lane & 31, l5 = lane >> 5;
  const int rbase = rt * 32;

  // ---- one-time stage (r5-proven): Wh -> bf16 LDS, 16B-granule swizzle
  {
    const int c  = tid >> 3;                 // 0..31  (local col)
    const int qb = (tid & 7) * 16;           // 16 x 16B chunks per thread
    const float* src = W + (size_t)(ct * 32 + c) * 2048 + 1024;
    char* dst = (char*)Bsm + c * 2048;
    const int sw = (c & 7) << 4;
#pragma unroll
    for (int q = qb; q < qb + 16; ++q) {
      float4 f0 = *(const float4*)(src + q * 8);
      float4 f1 = *(const float4*)(src + q * 8 + 4);
      uint4 w;
      w.x = cvtpk(f0.x, f0.y); w.y = cvtpk(f0.z, f0.w);
      w.z = cvtpk(f1.x, f1.y); w.w = cvtpk(f1.z, f1.w);
      *(uint4*)(dst + ((q * 16) ^ sw)) = w;
    }
  }
  __syncthreads();

  // B frag (r8-proven): col = ct*32 + l31, k = kq*256 + c*16 + l5*8
  const int swz = (l31 & 7) << 4;
  const char* bp = (char*)Bsm + l31 * 2048 + kq * 512;
  // C/D rows (m74/m101): row = (r&3) + 8*(r>>2) + 4*l5, col = l31
  int crow[16];
#pragma unroll
  for (int r = 0; r < 16; ++r) crow[r] = (r & 3) + 8 * (r >> 2) + 4 * l5;

  // repack indexing: thread -> (row, 4 cols)
  const int prow = tid >> 3, pcg = tid & 7;
  const int gr = rbase + prow;
  const int gc = ct * 32 + pcg * 4;

  uint2 xv;                                  // 4 bf16 of next step's xp

  // ---- step 0: h1 = tanh(xp[0])  (h0 == 0); store + prefetch xp[1]
  {
    uint2 x0 = *(const uint2*)(xp + (size_t)gr * H_ + gc);
    const ushort* xu = (const ushort*)&x0;
    float v0 = tanh_fast(bf2f(xu[0])), v1 = tanh_fast(bf2f(xu[1]));
    float v2 = tanh_fast(bf2f(xu[2])), v3 = tanh_fast(bf2f(xu[3]));
    uint2 o; o.x = cvtpk(v0, v1); o.y = cvtpk(v2, v3);
    st8_coh(hb + (size_t)gr * H_ + gc, o);
    xv = ld8_pf(xp + (size_t)BH + (size_t)gr * H_ + gc);
    asm volatile("s_waitcnt vmcnt(1)" ::: "memory");   // store drained
  }
  __syncthreads();
  if (tid == 0)
    __hip_atomic_store(flags + bid * 16, 1, __ATOMIC_RELAXED, __HIP_MEMORY_SCOPE_AGENT);
  if (tid < 32) {
    while (__hip_atomic_load(flags + (rt * 32 + tid) * 16, __ATOMIC_RELAXED,
                             __HIP_MEMORY_SCOPE_AGENT) < 1) {}
  }
  __syncthreads();

  for (int s = 1; s < T_; ++s) {
    const ushort* hprev = hb + ((s + 1) & 1) * BH;
    ushort*       hnext = hb + (s & 1) * BH;
    // A frag (r8-proven): row = rbase + l31, k = kq*256 + c*16 + l5*8
    const ushort* arow = hprev + (size_t)(rbase + l31) * H_ + kq * 256 + l5 * 8;

    // 16 disjoint sc1 A-loads (this wave's K-quarter)
    uint4 A[16];
#pragma unroll
    for (int c = 0; c < 16; ++c) A[c] = ld16_sc1(arow + c * 16);

    asm volatile("s_waitcnt vmcnt(8)" ::: "memory");   // pf + chunks 0..7 ready
    __builtin_amdgcn_sched_barrier(0);

    f32x16 acc;
#pragma unroll
    for (int i = 0; i < 16; ++i) acc[i] = 0.f;

#pragma unroll
    for (int c = 0; c < 8; ++c) {
      const int off = ((c * 32) | (l5 * 16)) ^ swz;
      acc = __builtin_amdgcn_mfma_f32_32x32x16_bf16(as_bf8(A[c]), *(const bf16x8*)(bp + off), acc, 0, 0, 0);
    }
    asm volatile("s_waitcnt vmcnt(0)" ::: "memory");
    __builtin_amdgcn_sched_barrier(0);
#pragma unroll
    for (int c = 8; c < 16; ++c) {
      const int off = ((c * 32) | (l5 * 16)) ^ swz;
      acc = __builtin_amdgcn_mfma_f32_32x32x16_bf16(as_bf8(A[c]), *(const bf16x8*)(bp + off), acc, 0, 0, 0);
    }

    // write this wave's K-quarter partials
#pragma unroll
    for (int r = 0; r < 16; ++r) Psm[kq][crow[r]][l31] = acc[r];
    __syncthreads();

    // repack combine: all 256 threads, (row, 4 cols) each
    f32x4 s4 = *(const f32x4*)&Psm[0][prow][pcg * 4]
             + *(const f32x4*)&Psm[1][prow][pcg * 4]
             + *(const f32x4*)&Psm[2][prow][pcg * 4]
             + *(const f32x4*)&Psm[3][prow][pcg * 4];
    const ushort* xu = (const ushort*)&xv;

    if (s < T_ - 1) {
      float v0 = tanh_fast(s4[0] + bf2f(xu[0])), v1 = tanh_fast(s4[1] + bf2f(xu[1]));
      float v2 = tanh_fast(s4[2] + bf2f(xu[2])), v3 = tanh_fast(s4[3] + bf2f(xu[3]));
      uint2 o; o.x = cvtpk(v0, v1); o.y = cvtpk(v2, v3);
      st8_coh(hnext + (size_t)gr * H_ + gc, o);
      xv = ld8_pf(xp + (size_t)(s + 1) * BH + (size_t)gr * H_ + gc);
      asm volatile("s_waitcnt vmcnt(1)" ::: "memory"); // store drained, pf flying
      __syncthreads();
      if (tid == 0)
        __hip_atomic_store(flags + bid * 16, s + 1, __ATOMIC_RELAXED, __HIP_MEMORY_SCOPE_AGENT);
      if (tid < 32) {
        while (__hip_atomic_load(flags + (rt * 32 + tid) * 16, __ATOMIC_RELAXED,
                                 __HIP_MEMORY_SCOPE_AGENT) < s + 1) {}
      }
      __syncthreads();
    } else {
      f32x4 o;
      o[0] = tanh_fast(s4[0] + bf2f(xu[0])); o[1] = tanh_fast(s4[1] + bf2f(xu[1]));
      o[2] = tanh_fast(s4[2] + bf2f(xu[2])); o[3] = tanh_fast(s4[3] + bf2f(xu[3]));
      *(f32x4*)(out + (size_t)gr * H_ + gc)               = o;
      *(f32x4*)(out + (size_t)BH + (size_t)gr * H_ + gc)  = o;
    }
  }
}

// ---------------------------------------------------------------------- host
extern "C" void kernel_launch(void* const* d_in, const int* in_sizes, int n_in,
                              void* d_out, int out_size, void* d_ws, size_t ws_size,
                              hipStream_t stream) {
  const float* xs   = (const float*)d_in[0];
  const float* W    = (const float*)d_in[1];
  const float* bias = (const float*)d_in[2];
  float* out = (float*)d_out;
  char*  ws  = (char*)d_ws;

  const size_t XP_OFF = 0;                       // bf16 x_proj (T,B,H): 256 MiB
  const size_t HB_OFF = 268435456;               // bf16 h double-buffer: 1 MiB
  const size_t BR_OFF = HB_OFF + 1048576;        // flags: 16 KiB (host memset)
  const size_t NEED   = BR_OFF + 16384;
  if (ws_size < NEED) {
    hipMemsetAsync(d_out, 0, (size_t)out_size * 4, stream);
    return;
  }

  ushort* xp    = (ushort*)(ws + XP_OFF);
  ushort* hb    = (ushort*)(ws + HB_OFF);
  int*    flags = (int*)(ws + BR_OFF);

  // flags must be fresh every call (ws not re-poisoned between replays)
  hipMemsetAsync(flags, 0, 256 * 16 * sizeof(int), stream);

  xproj_gemm<<<8192, 256, 0, stream>>>(xs, W, bias, xp);
  rnn_scan<<<256, 256, 0, stream>>>(W, xp, hb, out, flags);
}